// Round 3
// baseline (390.253 us; speedup 1.0000x reference)
//
#include <hip/hip_runtime.h>

#define N_NODES 100000
#define DIM 16
#define BSHIFT 7
#define BNODES 128                                  // nodes per bucket
#define NB ((N_NODES + BNODES - 1) / BNODES)        // 782 buckets
#define ACC_STRIDE 17                               // LDS pad: kills bank conflicts
#define TB 512

// ---------------- bucket-sort fast path ----------------

// A: per-workgroup histogram of dst-buckets (LDS atomics only).
__global__ __launch_bounds__(TB) void hist_kernel(const int* __restrict__ dst,
                                                  unsigned* __restrict__ H,
                                                  int E, int chunk) {
    __shared__ unsigned hist[NB];
    int tid = threadIdx.x;
    for (int i = tid; i < NB; i += TB) hist[i] = 0;
    __syncthreads();
    int e0 = blockIdx.x * chunk;
    int e1 = min(e0 + chunk, E);
    for (int e = e0 + tid; e < e1; e += TB)
        atomicAdd(&hist[((unsigned)dst[e]) >> BSHIFT], 1u);
    __syncthreads();
    unsigned* row = H + (size_t)blockIdx.x * NB;
    for (int i = tid; i < NB; i += TB) row[i] = hist[i];
}

// Block-wide exclusive scan (nthreads = TB or 1024, multiple of 64).
__device__ inline unsigned block_scan_excl(unsigned v, int tid, int nthreads,
                                           unsigned* warp_lds, unsigned* total_out) {
    unsigned x = v;
#pragma unroll
    for (int off = 1; off < 64; off <<= 1) {
        unsigned y = __shfl_up(x, off);
        if ((tid & 63) >= off) x += y;
    }
    int wid = tid >> 6;
    int nw = nthreads >> 6;
    if ((tid & 63) == 63) warp_lds[wid] = x;
    __syncthreads();
    if (tid < nw) {
        unsigned w = warp_lds[tid];
#pragma unroll
        for (int off = 1; off < 16; off <<= 1) {
            unsigned y = __shfl_up(w, off);
            if (tid >= off) w += y;
        }
        warp_lds[tid] = w;   // inclusive per-wave totals
    }
    __syncthreads();
    unsigned wbase = (wid > 0) ? warp_lds[wid - 1] : 0u;
    unsigned incl = x + wbase;
    if (total_out && tid == nthreads - 1) *total_out = incl;
    return incl - v;
}

// B1: for each bucket b, exclusive scan of H[wg][b] over wgs (in place) + total.
__global__ __launch_bounds__(TB) void scan_wg_kernel(unsigned* __restrict__ H,
                                                     unsigned* __restrict__ totals,
                                                     int nwg) {
    __shared__ unsigned warp_lds[16];
    int b = blockIdx.x;
    int tid = threadIdx.x;
    unsigned v = (tid < nwg) ? H[(size_t)tid * NB + b] : 0u;
    unsigned excl = block_scan_excl(v, tid, TB, warp_lds, &totals[b]);
    if (tid < nwg) H[(size_t)tid * NB + b] = excl;
}

// B2: exclusive scan of bucket totals -> bucket base offsets.
__global__ __launch_bounds__(1024) void scan_bucket_kernel(const unsigned* __restrict__ totals,
                                                           unsigned* __restrict__ base) {
    __shared__ unsigned warp_lds[16];
    int tid = threadIdx.x;
    unsigned v = (tid < NB) ? totals[tid] : 0u;
    unsigned excl = block_scan_excl(v, tid, 1024, warp_lds, nullptr);
    if (tid < NB) base[tid] = excl;
}

// C: place edge records into bucket-sorted order. LDS atomics for ranks only;
// global writes land in contiguous per-(wg,bucket) runs.
__global__ __launch_bounds__(TB) void place_kernel(const int* __restrict__ src,
                                                   const int* __restrict__ dst,
                                                   const float* __restrict__ probs,
                                                   const unsigned* __restrict__ O,
                                                   const unsigned* __restrict__ base,
                                                   unsigned long long* __restrict__ sorted,
                                                   int E, int chunk) {
    __shared__ unsigned cur[NB];
    int tid = threadIdx.x;
    const unsigned* row = O + (size_t)blockIdx.x * NB;
    for (int i = tid; i < NB; i += TB) cur[i] = base[i] + row[i];
    __syncthreads();
    int e0 = blockIdx.x * chunk;
    int e1 = min(e0 + chunk, E);
    for (int e = e0 + tid; e < e1; e += TB) {
        unsigned d = (unsigned)dst[e];
        unsigned s = (unsigned)src[e];
        float p = probs[e];
        unsigned b = d >> BSHIFT;
        unsigned pos = atomicAdd(&cur[b], 1u);
        unsigned lo = ((d & (BNODES - 1)) << 17) | s;   // src fits 17 bits
        sorted[pos] = ((unsigned long long)__float_as_uint(p) << 32) | lo;
    }
}

// D: one wg per bucket. Coalesced record reads, cached x-gather, LDS f32
// accumulate (stride-17), fused self-loop + clip + output write.
__global__ __launch_bounds__(TB) void bucket_accum_kernel(const float* __restrict__ x,
                                                          const float* __restrict__ weight,
                                                          const float* __restrict__ slw,
                                                          const unsigned* __restrict__ base,
                                                          const unsigned* __restrict__ totals,
                                                          const unsigned long long* __restrict__ sorted,
                                                          float* __restrict__ out) {
    __shared__ float accs[BNODES * ACC_STRIDE];
    int tid = threadIdx.x;
    int b = blockIdx.x;
    for (int i = tid; i < BNODES * ACC_STRIDE; i += TB) accs[i] = 0.0f;
    __syncthreads();
    unsigned s0 = base[b];
    unsigned cnt = totals[b];
    for (unsigned i = tid; i < cnt; i += TB) {
        unsigned long long rec = sorted[s0 + i];
        unsigned lo = (unsigned)rec;
        float p = __uint_as_float((unsigned)(rec >> 32));
        unsigned s = lo & 0x1FFFFu;
        unsigned dloc = (lo >> 17) & (BNODES - 1);
        const float4* xr = (const float4*)(x + (size_t)s * DIM);
        float* a = &accs[dloc * ACC_STRIDE];
#pragma unroll
        for (int q = 0; q < 4; ++q) {
            float4 xv = xr[q];
            atomicAdd(&a[q * 4 + 0], xv.x * p);
            atomicAdd(&a[q * 4 + 1], xv.y * p);
            atomicAdd(&a[q * 4 + 2], xv.z * p);
            atomicAdd(&a[q * 4 + 3], xv.w * p);
        }
    }
    __syncthreads();
    int n_loc = tid >> 2, q = tid & 3;      // 512 threads = 128 nodes x 4 quads
    int n = b * BNODES + n_loc;
    if (n < N_NODES) {
        float sc = 1.0f + slw[0];
        float4 xv = ((const float4*)x)[(size_t)n * 4 + q];
        float4 wv = ((const float4*)weight)[q];
        const float* a = &accs[n_loc * ACC_STRIDE + q * 4];
        float4 r;
        r.x = fminf(fmaxf(fmaf(xv.x, sc, a[0] * wv.x), 0.0f), 1.0f);
        r.y = fminf(fmaxf(fmaf(xv.y, sc, a[1] * wv.y), 0.0f), 1.0f);
        r.z = fminf(fmaxf(fmaf(xv.z, sc, a[2] * wv.z), 0.0f), 1.0f);
        r.w = fminf(fmaxf(fmaf(xv.w, sc, a[3] * wv.w), 0.0f), 1.0f);
        ((float4*)out)[(size_t)n * 4 + q] = r;
    }
}

// ---------------- fallback path (R1): direct float atomics ----------------

__global__ void diffusion_scatter_kernel(const float* __restrict__ x,
                                         const int* __restrict__ src,
                                         const int* __restrict__ dst,
                                         const float* __restrict__ probs,
                                         const float* __restrict__ weight,
                                         float* __restrict__ acc,
                                         int E) {
    int e = blockIdx.x * blockDim.x + threadIdx.x;
    if (e >= E) return;
    int s = src[e];
    int d = dst[e];
    float p = probs[e];
    const float4* xs = reinterpret_cast<const float4*>(x + (size_t)s * DIM);
    const float4* w4 = reinterpret_cast<const float4*>(weight);
    float* outp = acc + (size_t)d * DIM;
#pragma unroll
    for (int q = 0; q < 4; ++q) {
        float4 xv = xs[q];
        float4 wv = w4[q];
        atomicAdd(&outp[q * 4 + 0], xv.x * p * wv.x);
        atomicAdd(&outp[q * 4 + 1], xv.y * p * wv.y);
        atomicAdd(&outp[q * 4 + 2], xv.z * p * wv.z);
        atomicAdd(&outp[q * 4 + 3], xv.w * p * wv.w);
    }
}

__global__ void diffusion_finalize_kernel(const float* __restrict__ x,
                                          const float* __restrict__ slw,
                                          float* __restrict__ out,
                                          int n4) {
    int i = blockIdx.x * blockDim.x + threadIdx.x;
    if (i >= n4) return;
    float s = 1.0f + slw[0];
    float4 xv = reinterpret_cast<const float4*>(x)[i];
    float4 a = reinterpret_cast<float4*>(out)[i];
    float4 r;
    r.x = fminf(fmaxf(fmaf(xv.x, s, a.x), 0.0f), 1.0f);
    r.y = fminf(fmaxf(fmaf(xv.y, s, a.y), 0.0f), 1.0f);
    r.z = fminf(fmaxf(fmaf(xv.z, s, a.z), 0.0f), 1.0f);
    r.w = fminf(fmaxf(fmaf(xv.w, s, a.w), 0.0f), 1.0f);
    reinterpret_cast<float4*>(out)[i] = r;
}

extern "C" void kernel_launch(void* const* d_in, const int* in_sizes, int n_in,
                              void* d_out, int out_size, void* d_ws, size_t ws_size,
                              hipStream_t stream) {
    const float* x      = (const float*)d_in[0];
    const int*   eidx   = (const int*)d_in[1];   // [2, E]: row0=src, row1=dst
    const float* probs  = (const float*)d_in[2];
    const float* weight = (const float*)d_in[3];
    const float* slw    = (const float*)d_in[4];

    int E = in_sizes[2];
    float* out = (float*)d_out;

    // chunk sizing: keep nwg <= TB so the wg-scan fits one block
    int chunk = (E + TB - 1) / TB;
    if (chunk < 8192) chunk = 8192;
    int nwg = (E + chunk - 1) / chunk;

    // ws layout: H[nwg][NB] | totals[NB] | base[NB] | (align8) sorted[E] u64
    size_t H_elems = (size_t)nwg * NB;
    size_t head = (H_elems + 2 * (size_t)NB) * sizeof(unsigned);
    head = (head + 7) & ~(size_t)7;
    size_t need = head + (size_t)E * sizeof(unsigned long long);

    if (ws_size >= need) {
        unsigned* H = (unsigned*)d_ws;
        unsigned* totals = H + H_elems;
        unsigned* basep = totals + NB;
        unsigned long long* sorted = (unsigned long long*)((char*)d_ws + head);

        hist_kernel<<<nwg, TB, 0, stream>>>(eidx + E, H, E, chunk);
        scan_wg_kernel<<<NB, TB, 0, stream>>>(H, totals, nwg);
        scan_bucket_kernel<<<1, 1024, 0, stream>>>(totals, basep);
        place_kernel<<<nwg, TB, 0, stream>>>(eidx, eidx + E, probs, H, basep,
                                             sorted, E, chunk);
        bucket_accum_kernel<<<NB, TB, 0, stream>>>(x, weight, slw, basep, totals,
                                                   sorted, out);
    } else {
        const int T = 256;
        hipMemsetAsync(d_out, 0, (size_t)out_size * sizeof(float), stream);
        diffusion_scatter_kernel<<<(E + T - 1) / T, T, 0, stream>>>(
            x, eidx, eidx + E, probs, weight, out, E);
        int n4 = out_size / 4;
        diffusion_finalize_kernel<<<(n4 + T - 1) / T, T, 0, stream>>>(
            x, slw, out, n4);
    }
}

// Round 4
// 344.318 us; speedup vs baseline: 1.1334x; 1.1334x over previous
//
#include <hip/hip_runtime.h>

#define N_NODES 100000
#define DIM 16
#define BSHIFT 7
#define BNODES 128                                  // nodes per bucket
#define NB ((N_NODES + BNODES - 1) / BNODES)        // 782 buckets
#define ACC_STRIDE 17                               // LDS pad: kills bank conflicts
#define TB 512
#define SPLIT 4                                     // sub-workgroups per bucket in accum

// ---------------- bucket-sort fast path ----------------

// A: per-workgroup histogram of dst-buckets (LDS atomics only).
__global__ __launch_bounds__(TB) void hist_kernel(const int* __restrict__ dst,
                                                  unsigned* __restrict__ H,
                                                  int E, int chunk) {
    __shared__ unsigned hist[NB];
    int tid = threadIdx.x;
    for (int i = tid; i < NB; i += TB) hist[i] = 0;
    __syncthreads();
    int e0 = blockIdx.x * chunk;
    int e1 = min(e0 + chunk, E);
    for (int e = e0 + tid; e < e1; e += TB)
        atomicAdd(&hist[((unsigned)dst[e]) >> BSHIFT], 1u);
    __syncthreads();
    unsigned* row = H + (size_t)blockIdx.x * NB;
    for (int i = tid; i < NB; i += TB) row[i] = hist[i];
}

// Block-wide exclusive scan (nthreads = TB or 1024, multiple of 64).
__device__ inline unsigned block_scan_excl(unsigned v, int tid, int nthreads,
                                           unsigned* warp_lds, unsigned* total_out) {
    unsigned x = v;
#pragma unroll
    for (int off = 1; off < 64; off <<= 1) {
        unsigned y = __shfl_up(x, off);
        if ((tid & 63) >= off) x += y;
    }
    int wid = tid >> 6;
    int nw = nthreads >> 6;
    if ((tid & 63) == 63) warp_lds[wid] = x;
    __syncthreads();
    if (tid < nw) {
        unsigned w = warp_lds[tid];
#pragma unroll
        for (int off = 1; off < 16; off <<= 1) {
            unsigned y = __shfl_up(w, off);
            if (tid >= off) w += y;
        }
        warp_lds[tid] = w;   // inclusive per-wave totals
    }
    __syncthreads();
    unsigned wbase = (wid > 0) ? warp_lds[wid - 1] : 0u;
    unsigned incl = x + wbase;
    if (total_out && tid == nthreads - 1) *total_out = incl;
    return incl - v;
}

// B1: for each bucket b, exclusive scan of H[wg][b] over wgs (in place) + total.
__global__ __launch_bounds__(TB) void scan_wg_kernel(unsigned* __restrict__ H,
                                                     unsigned* __restrict__ totals,
                                                     int nwg) {
    __shared__ unsigned warp_lds[16];
    int b = blockIdx.x;
    int tid = threadIdx.x;
    unsigned v = (tid < nwg) ? H[(size_t)tid * NB + b] : 0u;
    unsigned excl = block_scan_excl(v, tid, TB, warp_lds, &totals[b]);
    if (tid < nwg) H[(size_t)tid * NB + b] = excl;
}

// B2: exclusive scan of bucket totals -> bucket base offsets.
__global__ __launch_bounds__(1024) void scan_bucket_kernel(const unsigned* __restrict__ totals,
                                                           unsigned* __restrict__ base) {
    __shared__ unsigned warp_lds[16];
    int tid = threadIdx.x;
    unsigned v = (tid < NB) ? totals[tid] : 0u;
    unsigned excl = block_scan_excl(v, tid, 1024, warp_lds, nullptr);
    if (tid < NB) base[tid] = excl;
}

// C: place edge records into bucket-sorted order. LDS atomics for ranks only;
// global writes land in contiguous per-(wg,bucket) runs.
__global__ __launch_bounds__(TB) void place_kernel(const int* __restrict__ src,
                                                   const int* __restrict__ dst,
                                                   const float* __restrict__ probs,
                                                   const unsigned* __restrict__ O,
                                                   const unsigned* __restrict__ base,
                                                   unsigned long long* __restrict__ sorted,
                                                   int E, int chunk) {
    __shared__ unsigned cur[NB];
    int tid = threadIdx.x;
    const unsigned* row = O + (size_t)blockIdx.x * NB;
    for (int i = tid; i < NB; i += TB) cur[i] = base[i] + row[i];
    __syncthreads();
    int e0 = blockIdx.x * chunk;
    int e1 = min(e0 + chunk, E);
    for (int e = e0 + tid; e < e1; e += TB) {
        unsigned d = (unsigned)dst[e];
        unsigned s = (unsigned)src[e];
        float p = probs[e];
        unsigned b = d >> BSHIFT;
        unsigned pos = atomicAdd(&cur[b], 1u);
        unsigned lo = ((d & (BNODES - 1)) << 17) | s;   // src fits 17 bits
        sorted[pos] = ((unsigned long long)__float_as_uint(p) << 32) | lo;
    }
}

// D: SPLIT sub-workgroups per bucket; 16 lanes per edge (one per dim).
// One coalesced 64B line request per edge; LDS f32 accumulate; raw partial dump.
__global__ __launch_bounds__(256) void accum_kernel(const float* __restrict__ x,
                                                    const unsigned* __restrict__ base,
                                                    const unsigned* __restrict__ totals,
                                                    const unsigned long long* __restrict__ sorted,
                                                    float* __restrict__ partial) {
    __shared__ float accs[BNODES * ACC_STRIDE];
    int tid = threadIdx.x;
    int bs = blockIdx.x;
    int b = bs >> 2;            // SPLIT == 4
    int sub = bs & 3;
    for (int i = tid; i < BNODES * ACC_STRIDE; i += 256) accs[i] = 0.0f;
    __syncthreads();
    unsigned s0 = base[b];
    unsigned cnt = totals[b];
    unsigned lo = s0 + (cnt * (unsigned)sub) / SPLIT;
    unsigned hi = s0 + (cnt * (unsigned)(sub + 1)) / SPLIT;
    int d = tid & 15;           // dim channel
    int slot = tid >> 4;        // 0..15 edge slots per 256-thread pass
#pragma unroll 2
    for (unsigned i = lo + slot; i < hi; i += 16) {
        unsigned long long rec = sorted[i];        // 16 lanes broadcast-read
        unsigned lo32 = (unsigned)rec;
        float p = __uint_as_float((unsigned)(rec >> 32));
        unsigned s = lo32 & 0x1FFFFu;
        unsigned dloc = (lo32 >> 17) & (BNODES - 1);
        float val = x[(size_t)s * DIM + d] * p;    // 16 consecutive dwords = 1 line
        atomicAdd(&accs[dloc * ACC_STRIDE + d], val);
    }
    __syncthreads();
    float* prow = partial + (size_t)bs * (BNODES * DIM);
    for (int k = tid; k < BNODES * DIM; k += 256)
        prow[k] = accs[(k >> 4) * ACC_STRIDE + (k & 15)];
}

// E: reduce SPLIT partials + self-loop + weight + clip -> out.
__global__ __launch_bounds__(256) void finalize_kernel(const float* __restrict__ x,
                                                       const float* __restrict__ weight,
                                                       const float* __restrict__ slw,
                                                       const float* __restrict__ partial,
                                                       float* __restrict__ out) {
    int i = blockIdx.x * 256 + threadIdx.x;   // quad index: node*4 + q
    int n = i >> 2, q = i & 3;
    if (n >= N_NODES) return;
    int b = n >> BSHIFT;
    int nloc = n & (BNODES - 1);
    float4 wv = ((const float4*)weight)[q];
    float4 a = make_float4(0.f, 0.f, 0.f, 0.f);
    size_t pbase = (size_t)(b * SPLIT) * (BNODES * DIM) + (size_t)nloc * DIM + q * 4;
#pragma unroll
    for (int s = 0; s < SPLIT; ++s) {
        float4 pv = *(const float4*)(partial + pbase + (size_t)s * (BNODES * DIM));
        a.x += pv.x; a.y += pv.y; a.z += pv.z; a.w += pv.w;
    }
    float sc = 1.0f + slw[0];
    float4 xv = ((const float4*)x)[i];
    float4 r;
    r.x = fminf(fmaxf(fmaf(xv.x, sc, a.x * wv.x), 0.0f), 1.0f);
    r.y = fminf(fmaxf(fmaf(xv.y, sc, a.y * wv.y), 0.0f), 1.0f);
    r.z = fminf(fmaxf(fmaf(xv.z, sc, a.z * wv.z), 0.0f), 1.0f);
    r.w = fminf(fmaxf(fmaf(xv.w, sc, a.w * wv.w), 0.0f), 1.0f);
    ((float4*)out)[i] = r;
}

// ---------------- fallback path (R1): direct float atomics ----------------

__global__ void diffusion_scatter_kernel(const float* __restrict__ x,
                                         const int* __restrict__ src,
                                         const int* __restrict__ dst,
                                         const float* __restrict__ probs,
                                         const float* __restrict__ weight,
                                         float* __restrict__ acc,
                                         int E) {
    int e = blockIdx.x * blockDim.x + threadIdx.x;
    if (e >= E) return;
    int s = src[e];
    int d = dst[e];
    float p = probs[e];
    const float4* xs = reinterpret_cast<const float4*>(x + (size_t)s * DIM);
    const float4* w4 = reinterpret_cast<const float4*>(weight);
    float* outp = acc + (size_t)d * DIM;
#pragma unroll
    for (int q = 0; q < 4; ++q) {
        float4 xv = xs[q];
        float4 wv = w4[q];
        atomicAdd(&outp[q * 4 + 0], xv.x * p * wv.x);
        atomicAdd(&outp[q * 4 + 1], xv.y * p * wv.y);
        atomicAdd(&outp[q * 4 + 2], xv.z * p * wv.z);
        atomicAdd(&outp[q * 4 + 3], xv.w * p * wv.w);
    }
}

__global__ void diffusion_finalize_kernel(const float* __restrict__ x,
                                          const float* __restrict__ slw,
                                          float* __restrict__ out,
                                          int n4) {
    int i = blockIdx.x * blockDim.x + threadIdx.x;
    if (i >= n4) return;
    float s = 1.0f + slw[0];
    float4 xv = reinterpret_cast<const float4*>(x)[i];
    float4 a = reinterpret_cast<float4*>(out)[i];
    float4 r;
    r.x = fminf(fmaxf(fmaf(xv.x, s, a.x), 0.0f), 1.0f);
    r.y = fminf(fmaxf(fmaf(xv.y, s, a.y), 0.0f), 1.0f);
    r.z = fminf(fmaxf(fmaf(xv.z, s, a.z), 0.0f), 1.0f);
    r.w = fminf(fmaxf(fmaf(xv.w, s, a.w), 0.0f), 1.0f);
    reinterpret_cast<float4*>(out)[i] = r;
}

extern "C" void kernel_launch(void* const* d_in, const int* in_sizes, int n_in,
                              void* d_out, int out_size, void* d_ws, size_t ws_size,
                              hipStream_t stream) {
    const float* x      = (const float*)d_in[0];
    const int*   eidx   = (const int*)d_in[1];   // [2, E]: row0=src, row1=dst
    const float* probs  = (const float*)d_in[2];
    const float* weight = (const float*)d_in[3];
    const float* slw    = (const float*)d_in[4];

    int E = in_sizes[2];
    float* out = (float*)d_out;

    // chunk sizing: keep nwg <= TB so the wg-scan fits one block
    int chunk = (E + TB - 1) / TB;
    if (chunk < 8192) chunk = 8192;
    int nwg = (E + chunk - 1) / chunk;

    // ws layout: H[nwg][NB] | totals[NB] | base[NB] | (align8) sorted[E] u64 | partial
    size_t H_elems = (size_t)nwg * NB;
    size_t head = (H_elems + 2 * (size_t)NB) * sizeof(unsigned);
    head = (head + 7) & ~(size_t)7;
    size_t sorted_bytes = (size_t)E * sizeof(unsigned long long);
    size_t partial_elems = (size_t)NB * SPLIT * BNODES * DIM;
    size_t need = head + sorted_bytes + partial_elems * sizeof(float);

    if (ws_size >= need) {
        unsigned* H = (unsigned*)d_ws;
        unsigned* totals = H + H_elems;
        unsigned* basep = totals + NB;
        unsigned long long* sorted = (unsigned long long*)((char*)d_ws + head);
        float* partial = (float*)((char*)d_ws + head + sorted_bytes);

        hist_kernel<<<nwg, TB, 0, stream>>>(eidx + E, H, E, chunk);
        scan_wg_kernel<<<NB, TB, 0, stream>>>(H, totals, nwg);
        scan_bucket_kernel<<<1, 1024, 0, stream>>>(totals, basep);
        place_kernel<<<nwg, TB, 0, stream>>>(eidx, eidx + E, probs, H, basep,
                                             sorted, E, chunk);
        accum_kernel<<<NB * SPLIT, 256, 0, stream>>>(x, basep, totals, sorted, partial);
        int nquad = N_NODES * 4;
        finalize_kernel<<<(nquad + 255) / 256, 256, 0, stream>>>(
            x, weight, slw, partial, out);
    } else {
        const int T = 256;
        hipMemsetAsync(d_out, 0, (size_t)out_size * sizeof(float), stream);
        diffusion_scatter_kernel<<<(E + T - 1) / T, T, 0, stream>>>(
            x, eidx, eidx + E, probs, weight, out, E);
        int n4 = out_size / 4;
        diffusion_finalize_kernel<<<(n4 + T - 1) / T, T, 0, stream>>>(
            x, slw, out, n4);
    }
}